// Round 4
// baseline (307.654 us; speedup 1.0000x reference)
//
#include <hip/hip_runtime.h>
#include <hip/hip_bf16.h>
#include <stdint.h>

#define B_ 8
#define N_ 2048
#define F_ 64
#define FH_ 64
#define H_ 4
#define C_ (H_*FH_)
#define LOG2E 1.44269504088896340736f

typedef short short8 __attribute__((ext_vector_type(8)));   // 8 bf16 raw bits (4 VGPRs)
typedef float f32x4 __attribute__((ext_vector_type(4)));

// float -> bf16 raw bits (RNE)
__device__ __forceinline__ short f2bf(float f) {
    __hip_bfloat16 h = __float2bfloat16(f);
    return __builtin_bit_cast(short, h);
}

// ---------------- K0: WT[h][o][f] = bf16(W[h][f][o]) ----------------
__global__ __launch_bounds__(256) void k0_wt(const float* __restrict__ W,
                                             __hip_bfloat16* __restrict__ WT) {
    int idx = blockIdx.x * 256 + threadIdx.x;   // 16384 elems total
    int h = idx >> 12, rem = idx & 4095, o = rem >> 6, f = rem & 63;
    WT[idx] = __float2bfloat16(W[(h * F_ + f) * FH_ + o]);
}

// ---------------- K1: featsT[b][h][o][n] = (X[b] @ W[h])^T via MFMA ----------------
// featsT = WT @ X^T : A-frag = WT rows (o), B-frag = X rows (n, contiguous in f)
__global__ __launch_bounds__(256) void k1_feats(const float* __restrict__ X,
                                                const __hip_bfloat16* __restrict__ WT,
                                                __hip_bfloat16* __restrict__ featsT) {
    const int nb = blockIdx.x, h = blockIdx.y, b = blockIdx.z;
    const int wave = threadIdx.x >> 6, lane = threadIdx.x & 63;
    const int m = lane & 15, q = lane >> 4;
    const int n = nb * 64 + wave * 16 + m;      // B-frag column (node index)
    f32x4 acc[4] = {};
#pragma unroll
    for (int ks = 0; ks < 2; ++ks) {            // K = F = 64, two steps of 32
        const float* xp = X + ((size_t)(b * N_ + n)) * F_ + ks * 32 + q * 8;
        float4 x0 = *(const float4*)xp;
        float4 x1 = *(const float4*)(xp + 4);
        short8 bfrag;
        bfrag[0] = f2bf(x0.x); bfrag[1] = f2bf(x0.y);
        bfrag[2] = f2bf(x0.z); bfrag[3] = f2bf(x0.w);
        bfrag[4] = f2bf(x1.x); bfrag[5] = f2bf(x1.y);
        bfrag[6] = f2bf(x1.z); bfrag[7] = f2bf(x1.w);
#pragma unroll
        for (int ot = 0; ot < 4; ++ot) {        // 64 output features = 4 row tiles
            short8 afrag = *(const short8*)(WT + ((size_t)(h * FH_ + ot * 16 + m)) * F_ + ks * 32 + q * 8);
            acc[ot] = __builtin_amdgcn_mfma_f32_16x16x32_bf16(afrag, bfrag, acc[ot], 0, 0, 0);
        }
    }
#pragma unroll
    for (int ot = 0; ot < 4; ++ot) {
#pragma unroll
        for (int r = 0; r < 4; ++r) {
            int orow = ot * 16 + q * 4 + r;     // C: row=(lane>>4)*4+r, col=lane&15
            featsT[((size_t)(b * H_ + h) * FH_ + orow) * N_ + n] = __float2bfloat16(acc[ot][r]);
        }
    }
}

// ---------------- K2: ss/sn[b][h][n] = log2(e) * X[b,n] . (W[h] @ a_{self,neigh}[h]) ----------------
__global__ __launch_bounds__(256) void k2_scores(const float* __restrict__ X,
                                                 const float* __restrict__ W,
                                                 const float* __restrict__ a_self,
                                                 const float* __restrict__ a_neigh,
                                                 float* __restrict__ ss, float* __restrict__ sn) {
    __shared__ float wl[2][H_][F_];
    const int tid = threadIdx.x;
    {   // each thread computes one (h,f) entry of the folded weight vectors
        int h = tid >> 6, f = tid & 63;
        float as_ = 0.f, an_ = 0.f;
#pragma unroll
        for (int o = 0; o < FH_; ++o) {
            float w = W[(h * F_ + f) * FH_ + o];
            as_ += w * a_self[h * FH_ + o];
            an_ += w * a_neigh[h * FH_ + o];
        }
        wl[0][h][f] = as_;
        wl[1][h][f] = an_;
    }
    __syncthreads();
    const int b = blockIdx.x >> 3;
    const int n = (blockIdx.x & 7) * 256 + tid;
    float xr[F_];
#pragma unroll
    for (int f = 0; f < F_; ++f) xr[f] = X[((size_t)(b * N_ + n)) * F_ + f];
#pragma unroll
    for (int h = 0; h < H_; ++h) {
        float ds = 0.f, dn = 0.f;
#pragma unroll
        for (int f = 0; f < F_; ++f) {
            ds += xr[f] * wl[0][h][f];
            dn += xr[f] * wl[1][h][f];
        }
        ss[((size_t)(b * H_ + h)) * N_ + n] = ds * LOG2E;
        sn[((size_t)(b * H_ + h)) * N_ + n] = dn * LOG2E;
    }
}

// ---------------- K3: fused mask+softmax(no-max)+PV MFMA + epilogue ----------------
// block = 256 threads = 4 waves; wave w = head w; block covers 32 rows of one batch.
__global__ __launch_bounds__(256) void k3_attn(const float* __restrict__ A,
                                               const __hip_bfloat16* __restrict__ featsT,
                                               const float* __restrict__ ss,
                                               const float* __restrict__ sn,
                                               const float* __restrict__ bias,
                                               float* __restrict__ out) {
    __shared__ float sn_lds[H_ * N_];           // 32 KB
    const int bx = blockIdx.x;
    const int b = bx >> 6;
    const int itile = bx & 63;
    const int tid = threadIdx.x;
    const int h = tid >> 6;
    const int lane = tid & 63;
    const int m = lane & 15, q = lane >> 4;
    const int ibase = itile * 32;

    {   // stage this head's (log2e-scaled) s_neigh row into LDS
        const float4* src = (const float4*)(sn + ((size_t)(b * H_ + h)) * N_);
        float4* dst = (float4*)(sn_lds + h * N_);
#pragma unroll
        for (int i = 0; i < 8; ++i) dst[lane + i * 64] = src[lane + i * 64];
    }
    const float ss0 = ss[((size_t)(b * H_ + h)) * N_ + ibase + m];
    const float ss1 = ss[((size_t)(b * H_ + h)) * N_ + ibase + 16 + m];
    __syncthreads();

    const float* arow0 = A + ((size_t)(b * N_ + ibase + m)) * N_ + q * 8;
    const float* arow1 = arow0 + (size_t)16 * N_;
    const __hip_bfloat16* fb = featsT + (((size_t)(b * H_ + h)) * FH_ + m) * N_ + q * 8;
    const float* snh = sn_lds + h * N_ + q * 8;

    f32x4 acc[2][4] = {};
    float l0 = 0.f, l1 = 0.f;

#pragma unroll 2
    for (int jb = 0; jb < N_; jb += 32) {
        float4 sv0 = *(const float4*)(snh + jb);
        float4 sv1 = *(const float4*)(snh + jb + 4);
        float4 a00 = *(const float4*)(arow0 + jb);
        float4 a01 = *(const float4*)(arow0 + jb + 4);
        float4 a10 = *(const float4*)(arow1 + jb);
        float4 a11 = *(const float4*)(arow1 + jb + 4);
        float snv[8] = {sv0.x, sv0.y, sv0.z, sv0.w, sv1.x, sv1.y, sv1.z, sv1.w};
        float ma[8]  = {a00.x, a00.y, a00.z, a00.w, a01.x, a01.y, a01.z, a01.w};
        float mb[8]  = {a10.x, a10.y, a10.z, a10.w, a11.x, a11.y, a11.z, a11.w};
        short8 p0, p1;
#pragma unroll
        for (int s = 0; s < 8; ++s) {
            // leaky_relu = max(x, 0.2x); inputs pre-scaled by log2(e) -> exp2
            float t0 = ss0 + snv[s];
            float t1 = ss1 + snv[s];
            float pa = ma[s] * exp2f(fmaxf(t0, 0.2f * t0));   // mask A in {0,1} exact
            float pb = mb[s] * exp2f(fmaxf(t1, 0.2f * t1));
            p0[s] = f2bf(pa);
            p1[s] = f2bf(pb);
            l0 += pa;
            l1 += pb;
        }
#pragma unroll
        for (int ct = 0; ct < 4; ++ct) {
            short8 fv = *(const short8*)(fb + (size_t)ct * 16 * N_ + jb);
            acc[0][ct] = __builtin_amdgcn_mfma_f32_16x16x32_bf16(p0, fv, acc[0][ct], 0, 0, 0);
            acc[1][ct] = __builtin_amdgcn_mfma_f32_16x16x32_bf16(p1, fv, acc[1][ct], 0, 0, 0);
        }
    }

    // reduce row-sums across the 4 lanes that share row m
    l0 += __shfl_xor(l0, 16); l0 += __shfl_xor(l0, 32);
    l1 += __shfl_xor(l1, 16); l1 += __shfl_xor(l1, 32);

    float bc[4];
#pragma unroll
    for (int ct = 0; ct < 4; ++ct) bc[ct] = bias[h * FH_ + ct * 16 + m];

#pragma unroll
    for (int sub = 0; sub < 2; ++sub) {
        float lsub = sub ? l1 : l0;
#pragma unroll
        for (int r = 0; r < 4; ++r) {
            int row_local = q * 4 + r;              // C layout: row=(lane>>4)*4+r
            float lv = __shfl(lsub, row_local);     // lane row_local holds that row's sum
            float inv = 1.0f / lv;
            int gr = ibase + sub * 16 + row_local;
#pragma unroll
            for (int ct = 0; ct < 4; ++ct) {
                float v = acc[sub][ct][r] * inv + bc[ct];
                out[((size_t)b * N_ + gr) * C_ + h * FH_ + ct * 16 + m] = fmaxf(v, 0.0f);
            }
        }
    }
}

extern "C" void kernel_launch(void* const* d_in, const int* in_sizes, int n_in,
                              void* d_out, int out_size, void* d_ws, size_t ws_size,
                              hipStream_t stream) {
    const float* X       = (const float*)d_in[0];
    const float* A       = (const float*)d_in[1];
    const float* W       = (const float*)d_in[2];
    const float* bias    = (const float*)d_in[3];
    const float* a_self  = (const float*)d_in[4];
    const float* a_neigh = (const float*)d_in[5];
    float* out = (float*)d_out;   // reference output dtype is float32

    char* ws = (char*)d_ws;
    __hip_bfloat16* featsT = (__hip_bfloat16*)(ws);             // 8 MB   [B][H][FH][N]
    __hip_bfloat16* WT     = (__hip_bfloat16*)(ws + 8388608);   // 32 KB  [H][FH][F]
    float* ss              = (float*)(ws + 8421376);            // 256 KB [B][H][N]
    float* sn              = (float*)(ws + 8683520);            // 256 KB [B][H][N]

    k0_wt    <<<64, 256, 0, stream>>>(W, WT);
    k1_feats <<<dim3(N_ / 64, H_, B_), 256, 0, stream>>>(X, WT, featsT);
    k2_scores<<<B_ * N_ / 256, 256, 0, stream>>>(X, W, a_self, a_neigh, ss, sn);
    k3_attn  <<<B_ * (N_ / 32), 256, 0, stream>>>(A, featsT, ss, sn, bias, out);
}